// Round 13
// baseline (152.149 us; speedup 1.0000x reference)
//
#include <hip/hip_runtime.h>
#include <hip/hip_bf16.h>
#include <cstddef>

typedef __attribute__((ext_vector_type(8))) short short8;   // 8 x bf16
typedef __attribute__((ext_vector_type(4))) float f32x4;    // MFMA accumulator

#define MFMA16(a, b, c) __builtin_amdgcn_mfma_f32_16x16x32_bf16((a), (b), (c), 0, 0, 0)

static __device__ __forceinline__ unsigned short f2bf(float f) {   // RNE
    unsigned int u = __float_as_uint(f);
    u = (u + 0x7FFFu + ((u >> 16) & 1u)) >> 16;
    return (unsigned short)u;
}
static __device__ __forceinline__ float bf2f(unsigned short h) {
    return __uint_as_float(((unsigned int)h) << 16);
}
static __device__ __forceinline__ float silu_f(float v) { return v / (1.f + expf(-v)); }

// 8 x f32 -> 8 x bf16 fragment via v_cvt_pk_bf16_f32 (RNE; verified r5-r12)
static __device__ __forceinline__ short8 cvt_frag(const float* __restrict__ p) {
    float4 a = *reinterpret_cast<const float4*>(p);
    float4 b = *reinterpret_cast<const float4*>(p + 4);
    union { short8 s; unsigned int u[4]; } r;
    asm("v_cvt_pk_bf16_f32 %0, %1, %2" : "=v"(r.u[0]) : "v"(a.x), "v"(a.y));
    asm("v_cvt_pk_bf16_f32 %0, %1, %2" : "=v"(r.u[1]) : "v"(a.z), "v"(a.w));
    asm("v_cvt_pk_bf16_f32 %0, %1, %2" : "=v"(r.u[2]) : "v"(b.x), "v"(b.y));
    asm("v_cvt_pk_bf16_f32 %0, %1, %2" : "=v"(r.u[3]) : "v"(b.z), "v"(b.w));
    return r.s;
}

// ws layout, bf16-element offsets (all multiples of 8 -> 16B aligned).
// x / wip are NOT staged (single-consumer: s1 reads them f32-direct).
enum : size_t {
    O_WXP   = 0,                        // 288 x 1024 (bf16 staged)
    O_WDT   = O_WXP  + 288 * 1024,      // 1024 x 32
    O_WOUT  = O_WDT  + 1024 * 32,       // 512 x 1024
    O_WFC1  = O_WOUT + 512 * 1024,      // 256 x 512
    O_XIN   = O_WFC1 + 256 * 512,       // 512 x 1024 (bf16 act)
    O_SZ    = O_XIN  + 512 * 1024,      // 512 x 1024
    O_Y     = O_SZ   + 512 * 1024,      // 512 x 1024
    O_F32   = O_Y    + 512 * 1024,      // f32 split-K accumulators below
};
#define N_XDBLF (512 * 288)             // f32
#define N_MOUTF (512 * 512)             // f32
#define N_ZERO  (N_XDBLF + N_MOUTF)

static __device__ __forceinline__ void cvt_seg(const float* __restrict__ s,
                                               unsigned short* __restrict__ d,
                                               int n, int gt, int np)
{
    for (int i = gt * 4; i < n; i += np * 4) {
        float4 v = *reinterpret_cast<const float4*>(s + i);
        ushort4 o;
        o.x = f2bf(v.x); o.y = f2bf(v.y); o.z = f2bf(v.z); o.w = f2bf(v.w);
        *reinterpret_cast<ushort4*>(d + i) = o;
    }
}

// ---------------------------------------------------------------------------
// Stage 1 (+ embedded staging): xz = x @ wip^T (M=512,N=2048,K=512) + conv/silu.
// Grid (32,32) = 1024 blocks (4/CU); wave = one 16x16 tile; x/wip f32-direct.
// Each block also converts a slice of the TAIL weights to bf16 and zeros the
// split-K f32 accumulators (independent work, no barrier needed).
// ---------------------------------------------------------------------------
__global__ __launch_bounds__(256, 4) void k_s1(
    const float* __restrict__ x,    const float* __restrict__ wip,
    const float* __restrict__ wxp,  const float* __restrict__ wdt,
    const float* __restrict__ wout, const float* __restrict__ wfc1,
    const float* __restrict__ cw,   const float* __restrict__ cb,
    unsigned short* __restrict__ wsb)
{
    const int tid = threadIdx.x;
    // ---- Part A: stage tail weights + zero accumulators (grid-strided) ----
    {
        const int gt = (blockIdx.y * 32 + blockIdx.x) * 256 + tid;
        const int np = 1024 * 256;
        cvt_seg(wxp,  wsb + O_WXP,  288 * 1024, gt, np);
        cvt_seg(wdt,  wsb + O_WDT,  1024 * 32,  gt, np);
        cvt_seg(wout, wsb + O_WOUT, 512 * 1024, gt, np);
        cvt_seg(wfc1, wsb + O_WFC1, 256 * 512,  gt, np);
        float* z = (float*)(wsb + O_F32);
        const float4 z4 = make_float4(0.f, 0.f, 0.f, 0.f);
        for (int i = gt * 4; i < N_ZERO; i += np * 4)
            *reinterpret_cast<float4*>(z + i) = z4;
    }
    // ---- Part B: s1 GEMM tile ----
    const int w = tid >> 6, lane = tid & 63, l15 = lane & 15, g = lane >> 4;
    const int n0 = blockIdx.x * 64 + w * 16;
    const int m0 = blockIdx.y * 16;

    const float* arow = x   + (size_t)(m0 + l15) * 512 + g * 8;
    const float* brow = wip + (size_t)(n0 + l15) * 512 + g * 8;

    f32x4 acc = {};
#pragma unroll 4
    for (int k0 = 0; k0 < 512; k0 += 32) {
        short8 a = cvt_frag(arow + k0);
        short8 b = cvt_frag(brow + k0);
        acc = MFMA16(a, b, acc);
    }
    const bool xhalf = (blockIdx.x < 16);
    unsigned short* dst = wsb + (xhalf ? O_XIN : O_SZ);
    int n = n0 + l15;                              // 0..2047
    int c = xhalf ? n : n - 1024;
    float cwv = 0.f, cbv = 0.f;
    if (xhalf) { cwv = cw[2 * n + 1]; cbv = cb[n]; }
#pragma unroll
    for (int i = 0; i < 4; ++i) {
        float v = acc[i];
        v = xhalf ? silu_f(cbv + cwv * v) : silu_f(v);
        dst[(size_t)(m0 + g * 4 + i) * 1024 + c] = f2bf(v);
    }
}

// ---------------------------------------------------------------------------
// Stage 2: xdbl_f32 += xin @ wxp^T (M=512,N=288,K=1024), split-K x4.
// Grid (18,8,4) = 576 blocks; block = 64 rows x 16 cols.
// ---------------------------------------------------------------------------
__global__ __launch_bounds__(256, 4) void k_s2(
    unsigned short* __restrict__ wsb, float* __restrict__ xdblf)
{
    const int tid = threadIdx.x;
    const int w = tid >> 6, lane = tid & 63, l15 = lane & 15, g = lane >> 4;
    const int n0 = blockIdx.x * 16;
    const int m0 = blockIdx.y * 64 + w * 16;
    const int kq = blockIdx.z * 256;

    const unsigned short* arow = wsb + O_XIN + (size_t)(m0 + l15) * 1024 + kq + g * 8;
    const unsigned short* brow = wsb + O_WXP + (size_t)(n0 + l15) * 1024 + kq + g * 8;

    f32x4 acc = {};
#pragma unroll 4
    for (int k0 = 0; k0 < 256; k0 += 32) {
        short8 a = *reinterpret_cast<const short8*>(arow + k0);
        short8 b = *reinterpret_cast<const short8*>(brow + k0);
        acc = MFMA16(a, b, acc);
    }
#pragma unroll
    for (int i = 0; i < 4; ++i)
        atomicAdd(&xdblf[(size_t)(m0 + g * 4 + i) * 288 + n0 + l15], acc[i]);
}

// ---------------------------------------------------------------------------
// Stage 3: bc[r] = Bm.Cm (f32, 128 terms); dt = softplus(xdbl[:,:32]@wdt^T+b);
//          y = xin * (dt*bc + D) * sz.
// Grid (16,32) = 512 blocks; wave = one 16x16 tile of y.
// ---------------------------------------------------------------------------
__global__ __launch_bounds__(256, 4) void k_s3(
    unsigned short* __restrict__ wsb, const float* __restrict__ xdblf,
    const float* __restrict__ dtb, const float* __restrict__ Dv)
{
    __shared__ float bcp[16][17];
    __shared__ float bc_s[16];
    const int tid = threadIdx.x;
    const int w = tid >> 6, lane = tid & 63, l15 = lane & 15, g = lane >> 4;
    const int n0 = blockIdx.x * 64;
    const int m0 = blockIdx.y * 16;

    {   // bc[r] = sum_{s<128} Bm[r,s]*Cm[r,s]  (f32 rows of xdbl)
        int r = tid >> 4, p = tid & 15;
        const float* row = xdblf + (size_t)(m0 + r) * 288;
        float s = 0.f;
#pragma unroll
        for (int q = 0; q < 8; ++q)
            s += row[32 + p * 8 + q] * row[160 + p * 8 + q];
        bcp[r][p] = s;
    }
    short8 a3 = cvt_frag(xdblf + (size_t)(m0 + l15) * 288 + g * 8);   // cols 0..31
    __syncthreads();
    if (tid < 16) {
        float s = 0.f;
#pragma unroll
        for (int p = 0; p < 16; ++p) s += bcp[tid][p];
        bc_s[tid] = s;
    }
    __syncthreads();

    const unsigned short* xinb = wsb + O_XIN;
    const unsigned short* szb  = wsb + O_SZ;
    unsigned short* yb = wsb + O_Y;
    const f32x4 z4 = {0.f, 0.f, 0.f, 0.f};
    int n = n0 + w * 16 + l15;                     // 0..1023
    short8 b = *reinterpret_cast<const short8*>(wsb + O_WDT + (size_t)n * 32 + g * 8);
    f32x4 acc = MFMA16(a3, b, z4);
    float dtbv = dtb[n], Dvv = Dv[n];
#pragma unroll
    for (int i = 0; i < 4; ++i) {
        int r = m0 + g * 4 + i;
        float dtv = acc[i] + dtbv;
        dtv = (dtv > 20.f) ? dtv : log1pf(expf(dtv));   // softplus
        float yv = bf2f(xinb[(size_t)r * 1024 + n]) *
                   (dtv * bc_s[g * 4 + i] + Dvv) *
                   bf2f(szb[(size_t)r * 1024 + n]);
        yb[(size_t)r * 1024 + n] = f2bf(yv);
    }
}

// ---------------------------------------------------------------------------
// Stage 4: mout_f32 += y @ wout^T (M=512,N=512,K=1024), split-K x2.
// Grid (8,32,2) = 512 blocks; block = 16 rows x 64 cols.
// ---------------------------------------------------------------------------
__global__ __launch_bounds__(256, 4) void k_s4(
    unsigned short* __restrict__ wsb, float* __restrict__ moutf)
{
    const int tid = threadIdx.x;
    const int w = tid >> 6, lane = tid & 63, l15 = lane & 15, g = lane >> 4;
    const int n0 = blockIdx.x * 64 + w * 16;
    const int m0 = blockIdx.y * 16;
    const int kq = blockIdx.z * 512;

    const unsigned short* arow = wsb + O_Y    + (size_t)(m0 + l15) * 1024 + kq + g * 8;
    const unsigned short* brow = wsb + O_WOUT + (size_t)(n0 + l15) * 1024 + kq + g * 8;

    f32x4 acc = {};
#pragma unroll 4
    for (int k0 = 0; k0 < 512; k0 += 32) {
        short8 a = *reinterpret_cast<const short8*>(arow + k0);
        short8 b = *reinterpret_cast<const short8*>(brow + k0);
        acc = MFMA16(a, b, acc);
    }
#pragma unroll
    for (int i = 0; i < 4; ++i)
        atomicAdd(&moutf[(size_t)(m0 + g * 4 + i) * 512 + n0 + l15], acc[i]);
}

// ---------------------------------------------------------------------------
// Stage 5: h1 = mout @ fc1_w^T (M=512,N=256,K=512) + head.
// Grid 32 x 512 thr; A f32 via cvt_frag, B staged bf16; LDS reduce.
// ---------------------------------------------------------------------------
__global__ __launch_bounds__(512, 2) void k_s5(
    const float* __restrict__ moutf, unsigned short* __restrict__ wsb,
    const float* __restrict__ bfc1, const float* __restrict__ wfc5,
    const float* __restrict__ bfc5, float* __restrict__ out)
{
    __shared__ float red[16][8];
    const int tid = threadIdx.x;
    const int w = tid >> 6, lane = tid & 63, l15 = lane & 15, g = lane >> 4;
    const int m0 = blockIdx.x * 16;

    const float* arow = moutf + (size_t)(m0 + l15) * 512 + g * 8;
    const unsigned short* brow = wsb + O_WFC1 + (size_t)(w * 32 + l15) * 512 + g * 8;

    f32x4 acc[2] = {};
#pragma unroll 4
    for (int k0 = 0; k0 < 512; k0 += 32) {
        short8 a = cvt_frag(arow + k0);
#pragma unroll
        for (int f = 0; f < 2; ++f) {
            short8 b = *reinterpret_cast<const short8*>(brow + (size_t)f * 16 * 512 + k0);
            acc[f] = MFMA16(a, b, acc[f]);
        }
    }
    float part[4] = {0.f, 0.f, 0.f, 0.f};
#pragma unroll
    for (int f = 0; f < 2; ++f) {
        int n = w * 32 + f * 16 + l15;             // 0..255
        float b1 = bfc1[n], w5 = wfc5[n];
#pragma unroll
        for (int i = 0; i < 4; ++i) {
            float v = acc[f][i] + b1;
            v = v >= 0.f ? v : 0.1f * v;           // leaky relu
            part[i] = fmaf(v, w5, part[i]);
        }
    }
#pragma unroll
    for (int off = 1; off < 16; off <<= 1)
#pragma unroll
        for (int i = 0; i < 4; ++i) part[i] += __shfl_xor(part[i], off, 64);
    if (l15 == 0)
#pragma unroll
        for (int i = 0; i < 4; ++i) red[g * 4 + i][w] = part[i];
    __syncthreads();
    if (tid < 16) {
        float s = 0.f;
#pragma unroll
        for (int j = 0; j < 8; ++j) s += red[tid][j];
        out[m0 + tid] = 1.f / (1.f + expf(-(s + bfc5[0])));
    }
}

// ---------------------------------------------------------------------------
extern "C" void kernel_launch(void* const* d_in, const int* in_sizes, int n_in,
                              void* d_out, int out_size, void* d_ws, size_t ws_size,
                              hipStream_t stream)
{
    const float* x    = (const float*)d_in[0];
    const float* wip  = (const float*)d_in[1];
    const float* cw   = (const float*)d_in[2];
    const float* cb   = (const float*)d_in[3];
    const float* wxp  = (const float*)d_in[4];
    const float* wdt  = (const float*)d_in[5];
    const float* bdt  = (const float*)d_in[6];
    // d_in[7] = A_log: unused — h0 == 0 at L==1 so dA never contributes.
    const float* Dv   = (const float*)d_in[8];
    const float* wout = (const float*)d_in[9];
    const float* wfc1 = (const float*)d_in[10];
    const float* bfc1 = (const float*)d_in[11];
    const float* wfc5 = (const float*)d_in[12];
    const float* bfc5 = (const float*)d_in[13];
    float* out = (float*)d_out;

    unsigned short* wsb = (unsigned short*)d_ws;
    float* xdblf = (float*)(wsb + O_F32);
    float* moutf = xdblf + N_XDBLF;

    k_s1<<<dim3(32, 32),   256, 0, stream>>>(x, wip, wxp, wdt, wout, wfc1, cw, cb, wsb);
    k_s2<<<dim3(18, 8, 4), 256, 0, stream>>>(wsb, xdblf);
    k_s3<<<dim3(16, 32),   256, 0, stream>>>(wsb, xdblf, bdt, Dv);
    k_s4<<<dim3(8, 32, 2), 256, 0, stream>>>(wsb, moutf);
    k_s5<<<dim3(32),       512, 0, stream>>>(moutf, wsb, bfc1, wfc5, bfc5, out);
}

// Round 14
// 149.507 us; speedup vs baseline: 1.0177x; 1.0177x over previous
//
#include <hip/hip_runtime.h>
#include <hip/hip_bf16.h>
#include <cstddef>

typedef __attribute__((ext_vector_type(8))) short short8;   // 8 x bf16
typedef __attribute__((ext_vector_type(4))) float f32x4;    // MFMA accumulator

#define MFMA16(a, b, c) __builtin_amdgcn_mfma_f32_16x16x32_bf16((a), (b), (c), 0, 0, 0)

static __device__ __forceinline__ unsigned short f2bf(float f) {   // RNE
    unsigned int u = __float_as_uint(f);
    u = (u + 0x7FFFu + ((u >> 16) & 1u)) >> 16;
    return (unsigned short)u;
}
static __device__ __forceinline__ float bf2f(unsigned short h) {
    return __uint_as_float(((unsigned int)h) << 16);
}
static __device__ __forceinline__ float silu_f(float v) { return v / (1.f + expf(-v)); }

// 8 x f32 -> 8 x bf16 fragment via v_cvt_pk_bf16_f32 (RNE; verified r5-r13)
static __device__ __forceinline__ short8 cvt_frag(const float* __restrict__ p) {
    float4 a = *reinterpret_cast<const float4*>(p);
    float4 b = *reinterpret_cast<const float4*>(p + 4);
    union { short8 s; unsigned int u[4]; } r;
    asm("v_cvt_pk_bf16_f32 %0, %1, %2" : "=v"(r.u[0]) : "v"(a.x), "v"(a.y));
    asm("v_cvt_pk_bf16_f32 %0, %1, %2" : "=v"(r.u[1]) : "v"(a.z), "v"(a.w));
    asm("v_cvt_pk_bf16_f32 %0, %1, %2" : "=v"(r.u[2]) : "v"(b.x), "v"(b.y));
    asm("v_cvt_pk_bf16_f32 %0, %1, %2" : "=v"(r.u[3]) : "v"(b.z), "v"(b.w));
    return r.s;
}

// ws layout, bf16-element offsets (all multiples of 8 -> 16B aligned)
enum : size_t {
    O_X     = 0,                        // 512 x 512   (staged bf16)
    O_WIP   = O_X    + 512 * 512,       // 2048 x 512
    O_WXP   = O_WIP  + 2048 * 512,      // 288 x 1024
    O_WDT   = O_WXP  + 288 * 1024,      // 1024 x 32
    O_W45   = O_WDT  + 1024 * 32,       // 256 x 1024  (fused wfc1@wout, bf16)
    O_XIN   = O_W45  + 256 * 1024,      // 512 x 1024  (bf16 act)
    O_SZ    = O_XIN  + 512 * 1024,      // 512 x 1024
    O_Y     = O_SZ   + 512 * 1024,      // 512 x 1024
    O_F32   = O_Y    + 512 * 1024,      // f32 split-K accumulator (xdbl)
};
#define N_XDBLF (512 * 288)             // f32

static __device__ __forceinline__ void cvt_seg(const float* __restrict__ s,
                                               unsigned short* __restrict__ d,
                                               int n, int gt, int np)
{
    for (int i = gt * 4; i < n; i += np * 4) {
        float4 v = *reinterpret_cast<const float4*>(s + i);
        ushort4 o;
        o.x = f2bf(v.x); o.y = f2bf(v.y); o.z = f2bf(v.z); o.w = f2bf(v.w);
        *reinterpret_cast<ushort4*>(d + i) = o;
    }
}

// ---------------------------------------------------------------------------
// k_prep: stage x/wip/wxp/wdt f32->bf16; zero xdbl f32 accumulator; compute
// W45 = wfc1 @ wout (256x1024, K=512) in blocks 0..255 (out_proj and fc1 are
// back-to-back linears -> fold them; stage 4 disappears).
// W45[j,c] = sum_d wfc1[j,d] * wout[d,c]; wout tiles LDS-transposed.
// ---------------------------------------------------------------------------
__global__ __launch_bounds__(256) void k_prep(
    const float* __restrict__ x,    const float* __restrict__ wip,
    const float* __restrict__ wxp,  const float* __restrict__ wdt,
    const float* __restrict__ wout, const float* __restrict__ wfc1,
    unsigned short* __restrict__ wsb)
{
    const int tid = threadIdx.x;
    const int bid = blockIdx.x;
    {   // grid-strided staging + zeroing (all 1024 blocks)
        const int gt = bid * 256 + tid, np = 1024 * 256;
        cvt_seg(x,   wsb + O_X,   512 * 512,  gt, np);
        cvt_seg(wip, wsb + O_WIP, 2048 * 512, gt, np);
        cvt_seg(wxp, wsb + O_WXP, 288 * 1024, gt, np);
        cvt_seg(wdt, wsb + O_WDT, 1024 * 32,  gt, np);
        float* z = (float*)(wsb + O_F32);
        const float4 z4 = make_float4(0.f, 0.f, 0.f, 0.f);
        for (int i = gt * 4; i < N_XDBLF; i += np * 4)
            *reinterpret_cast<float4*>(z + i) = z4;
    }
    if (bid < 256) {    // W45 tile: 16 j-rows x 64 c-cols per block
        __shared__ __align__(16) float t[64][36];   // wout chunk transposed [c][d]
        const int w = tid >> 6, lane = tid & 63, l15 = lane & 15, g = lane >> 4;
        const int j0 = (bid >> 4) * 16;
        const int c0 = (bid & 15) * 64;
        f32x4 acc = {};
        for (int d0 = 0; d0 < 512; d0 += 32) {
            int r = tid >> 3, cc = (tid & 7) * 8;   // 32 d-rows x 64 c-cols
            float4 v0 = *reinterpret_cast<const float4*>(wout + (size_t)(d0 + r) * 1024 + c0 + cc);
            float4 v1 = *reinterpret_cast<const float4*>(wout + (size_t)(d0 + r) * 1024 + c0 + cc + 4);
            t[cc + 0][r] = v0.x; t[cc + 1][r] = v0.y; t[cc + 2][r] = v0.z; t[cc + 3][r] = v0.w;
            t[cc + 4][r] = v1.x; t[cc + 5][r] = v1.y; t[cc + 6][r] = v1.z; t[cc + 7][r] = v1.w;
            __syncthreads();
            short8 a = cvt_frag(wfc1 + (size_t)(j0 + l15) * 512 + d0 + g * 8);
            short8 b = cvt_frag(&t[w * 16 + l15][g * 8]);
            acc = MFMA16(a, b, acc);
            __syncthreads();
        }
        unsigned short* w45 = wsb + O_W45;
        int c = c0 + w * 16 + l15;
#pragma unroll
        for (int i = 0; i < 4; ++i)
            w45[(size_t)(j0 + g * 4 + i) * 1024 + c] = f2bf(acc[i]);
    }
}

// ---------------------------------------------------------------------------
// Stage 1: xz = x @ wip^T (M=512,N=2048,K=512) + conv/silu.
// Grid (32,32) = 1024 blocks (4/CU); wave = one 16x16 tile; staged bf16.
// ---------------------------------------------------------------------------
__global__ __launch_bounds__(256, 4) void k_s1(
    unsigned short* __restrict__ wsb,
    const float* __restrict__ cw, const float* __restrict__ cb)
{
    const int tid = threadIdx.x;
    const int w = tid >> 6, lane = tid & 63, l15 = lane & 15, g = lane >> 4;
    const int n0 = blockIdx.x * 64 + w * 16;
    const int m0 = blockIdx.y * 16;

    const unsigned short* arow = wsb + O_X   + (size_t)(m0 + l15) * 512 + g * 8;
    const unsigned short* brow = wsb + O_WIP + (size_t)(n0 + l15) * 512 + g * 8;

    f32x4 acc = {};
#pragma unroll 4
    for (int k0 = 0; k0 < 512; k0 += 32) {
        short8 a = *reinterpret_cast<const short8*>(arow + k0);
        short8 b = *reinterpret_cast<const short8*>(brow + k0);
        acc = MFMA16(a, b, acc);
    }
    const bool xhalf = (blockIdx.x < 16);
    unsigned short* dst = wsb + (xhalf ? O_XIN : O_SZ);
    int n = n0 + l15;                              // 0..2047
    int c = xhalf ? n : n - 1024;
    float cwv = 0.f, cbv = 0.f;
    if (xhalf) { cwv = cw[2 * n + 1]; cbv = cb[n]; }
#pragma unroll
    for (int i = 0; i < 4; ++i) {
        float v = acc[i];
        v = xhalf ? silu_f(cbv + cwv * v) : silu_f(v);
        dst[(size_t)(m0 + g * 4 + i) * 1024 + c] = f2bf(v);
    }
}

// ---------------------------------------------------------------------------
// Stage 2: xdbl_f32 += xin @ wxp^T (M=512,N=288,K=1024), split-K x4.
// Grid (18,8,4) = 576 blocks; block = 64 rows x 16 cols.
// ---------------------------------------------------------------------------
__global__ __launch_bounds__(256, 4) void k_s2(
    unsigned short* __restrict__ wsb, float* __restrict__ xdblf)
{
    const int tid = threadIdx.x;
    const int w = tid >> 6, lane = tid & 63, l15 = lane & 15, g = lane >> 4;
    const int n0 = blockIdx.x * 16;
    const int m0 = blockIdx.y * 64 + w * 16;
    const int kq = blockIdx.z * 256;

    const unsigned short* arow = wsb + O_XIN + (size_t)(m0 + l15) * 1024 + kq + g * 8;
    const unsigned short* brow = wsb + O_WXP + (size_t)(n0 + l15) * 1024 + kq + g * 8;

    f32x4 acc = {};
#pragma unroll 4
    for (int k0 = 0; k0 < 256; k0 += 32) {
        short8 a = *reinterpret_cast<const short8*>(arow + k0);
        short8 b = *reinterpret_cast<const short8*>(brow + k0);
        acc = MFMA16(a, b, acc);
    }
#pragma unroll
    for (int i = 0; i < 4; ++i)
        atomicAdd(&xdblf[(size_t)(m0 + g * 4 + i) * 288 + n0 + l15], acc[i]);
}

// ---------------------------------------------------------------------------
// Stage 3: bc[r] = Bm.Cm (f32, 128 terms); dt = softplus(xdbl[:,:32]@wdt^T+b);
//          y = xin * (dt*bc + D) * sz.
// Grid (16,32) = 512 blocks; wave = one 16x16 tile of y.
// ---------------------------------------------------------------------------
__global__ __launch_bounds__(256, 4) void k_s3(
    unsigned short* __restrict__ wsb, const float* __restrict__ xdblf,
    const float* __restrict__ dtb, const float* __restrict__ Dv)
{
    __shared__ float bcp[16][17];
    __shared__ float bc_s[16];
    const int tid = threadIdx.x;
    const int w = tid >> 6, lane = tid & 63, l15 = lane & 15, g = lane >> 4;
    const int n0 = blockIdx.x * 64;
    const int m0 = blockIdx.y * 16;

    {   // bc[r] = sum_{s<128} Bm[r,s]*Cm[r,s]  (f32 rows of xdbl)
        int r = tid >> 4, p = tid & 15;
        const float* row = xdblf + (size_t)(m0 + r) * 288;
        float s = 0.f;
#pragma unroll
        for (int q = 0; q < 8; ++q)
            s += row[32 + p * 8 + q] * row[160 + p * 8 + q];
        bcp[r][p] = s;
    }
    short8 a3 = cvt_frag(xdblf + (size_t)(m0 + l15) * 288 + g * 8);   // cols 0..31
    __syncthreads();
    if (tid < 16) {
        float s = 0.f;
#pragma unroll
        for (int p = 0; p < 16; ++p) s += bcp[tid][p];
        bc_s[tid] = s;
    }
    __syncthreads();

    const unsigned short* xinb = wsb + O_XIN;
    const unsigned short* szb  = wsb + O_SZ;
    unsigned short* yb = wsb + O_Y;
    const f32x4 z4 = {0.f, 0.f, 0.f, 0.f};
    int n = n0 + w * 16 + l15;                     // 0..1023
    short8 b = *reinterpret_cast<const short8*>(wsb + O_WDT + (size_t)n * 32 + g * 8);
    f32x4 acc = MFMA16(a3, b, z4);
    float dtbv = dtb[n], Dvv = Dv[n];
#pragma unroll
    for (int i = 0; i < 4; ++i) {
        int r = m0 + g * 4 + i;
        float dtv = acc[i] + dtbv;
        dtv = (dtv > 20.f) ? dtv : log1pf(expf(dtv));   // softplus
        float yv = bf2f(xinb[(size_t)r * 1024 + n]) *
                   (dtv * bc_s[g * 4 + i] + Dvv) *
                   bf2f(szb[(size_t)r * 1024 + n]);
        yb[(size_t)r * 1024 + n] = f2bf(yv);
    }
}

// ---------------------------------------------------------------------------
// Stage 4+5 folded: h1 = y @ W45^T (M=512,N=256,K=1024) + head:
//   out[b] = sigmoid(fc5_b + sum_j fc5_w[j] * leaky(h1[b,j] + fc1_b[j])).
// Grid 32 blocks x 512 threads; wave w = j-cols w*32..w*32+32; LDS reduce.
// ---------------------------------------------------------------------------
__global__ __launch_bounds__(512, 2) void k_s45(
    unsigned short* __restrict__ wsb,
    const float* __restrict__ bfc1, const float* __restrict__ wfc5,
    const float* __restrict__ bfc5, float* __restrict__ out)
{
    __shared__ float red[16][8];
    const int tid = threadIdx.x;
    const int w = tid >> 6, lane = tid & 63, l15 = lane & 15, g = lane >> 4;
    const int m0 = blockIdx.x * 16;

    const unsigned short* arow = wsb + O_Y   + (size_t)(m0 + l15) * 1024 + g * 8;
    const unsigned short* brow = wsb + O_W45 + (size_t)(w * 32 + l15) * 1024 + g * 8;

    f32x4 acc[2] = {};
#pragma unroll 4
    for (int k0 = 0; k0 < 1024; k0 += 32) {
        short8 a = *reinterpret_cast<const short8*>(arow + k0);
#pragma unroll
        for (int f = 0; f < 2; ++f) {
            short8 b = *reinterpret_cast<const short8*>(brow + (size_t)f * 16 * 1024 + k0);
            acc[f] = MFMA16(a, b, acc[f]);
        }
    }
    float part[4] = {0.f, 0.f, 0.f, 0.f};
#pragma unroll
    for (int f = 0; f < 2; ++f) {
        int n = w * 32 + f * 16 + l15;             // j in 0..255
        float b1 = bfc1[n], w5 = wfc5[n];
#pragma unroll
        for (int i = 0; i < 4; ++i) {
            float v = acc[f][i] + b1;
            v = v >= 0.f ? v : 0.1f * v;           // leaky relu
            part[i] = fmaf(v, w5, part[i]);
        }
    }
#pragma unroll
    for (int off = 1; off < 16; off <<= 1)
#pragma unroll
        for (int i = 0; i < 4; ++i) part[i] += __shfl_xor(part[i], off, 64);
    if (l15 == 0)
#pragma unroll
        for (int i = 0; i < 4; ++i) red[g * 4 + i][w] = part[i];
    __syncthreads();
    if (tid < 16) {
        float s = 0.f;
#pragma unroll
        for (int j = 0; j < 8; ++j) s += red[tid][j];
        out[m0 + tid] = 1.f / (1.f + expf(-(s + bfc5[0])));
    }
}

// ---------------------------------------------------------------------------
extern "C" void kernel_launch(void* const* d_in, const int* in_sizes, int n_in,
                              void* d_out, int out_size, void* d_ws, size_t ws_size,
                              hipStream_t stream)
{
    const float* x    = (const float*)d_in[0];
    const float* wip  = (const float*)d_in[1];
    const float* cw   = (const float*)d_in[2];
    const float* cb   = (const float*)d_in[3];
    const float* wxp  = (const float*)d_in[4];
    const float* wdt  = (const float*)d_in[5];
    const float* bdt  = (const float*)d_in[6];
    // d_in[7] = A_log: unused — h0 == 0 at L==1 so dA never contributes.
    const float* Dv   = (const float*)d_in[8];
    const float* wout = (const float*)d_in[9];
    const float* wfc1 = (const float*)d_in[10];
    const float* bfc1 = (const float*)d_in[11];
    const float* wfc5 = (const float*)d_in[12];
    const float* bfc5 = (const float*)d_in[13];
    float* out = (float*)d_out;

    unsigned short* wsb = (unsigned short*)d_ws;
    float* xdblf = (float*)(wsb + O_F32);

    k_prep<<<dim3(1024),    256, 0, stream>>>(x, wip, wxp, wdt, wout, wfc1, wsb);
    k_s1  <<<dim3(32, 32),  256, 0, stream>>>(wsb, cw, cb);
    k_s2  <<<dim3(18, 8, 4),256, 0, stream>>>(wsb, xdblf);
    k_s3  <<<dim3(16, 32),  256, 0, stream>>>(wsb, xdblf, bdt, Dv);
    k_s45 <<<dim3(32),      512, 0, stream>>>(wsb, bfc1, wfc5, bfc5, out);
}